// Round 8
// baseline (496.238 us; speedup 1.0000x reference)
//
#include <hip/hip_runtime.h>
#include <stdint.h>

typedef __attribute__((ext_vector_type(4))) float f32x4;
typedef __attribute__((ext_vector_type(8))) __bf16 bf16x8;

__device__ __forceinline__ uint16_t f2bf(float f) {
  uint32_t u = __builtin_bit_cast(uint32_t, f);
  u += 0x7FFFu + ((u >> 16) & 1u);
  return (uint16_t)(u >> 16);
}

__device__ __forceinline__ float bf2f(uint16_t u) {
  uint32_t v = ((uint32_t)u) << 16;
  return __builtin_bit_cast(float, v);
}

__device__ __forceinline__ void load_lds16(const uint16_t* g, uint16_t* l) {
  __builtin_amdgcn_global_load_lds((const __attribute__((address_space(1))) void*)g,
                                   (__attribute__((address_space(3))) void*)l, 16, 0, 0);
}

// ---------------- fused prep: convert x+ctx to bf16, transpose 3 W's ----------------
__global__ __launch_bounds__(256) void k_prep(const float* __restrict__ x,
                                              const float* __restrict__ ctx,
                                              const float* __restrict__ Wq,
                                              const float* __restrict__ Wkv,
                                              const float* __restrict__ Wout,
                                              uint16_t* __restrict__ xb,
                                              uint16_t* __restrict__ ctxb,
                                              uint16_t* __restrict__ wqt,
                                              uint16_t* __restrict__ wkvt,
                                              uint16_t* __restrict__ woutt,
                                              float qscale) {
  __shared__ float tile[32][33];
  int id = blockIdx.x;
  int tid = threadIdx.x;
  if (id < 10240) {
    const float* in;
    uint16_t* out;
    int j = id * 256 + tid;
    if (j < 524288) { in = x; out = xb; }
    else            { in = ctx; out = ctxb; j -= 524288; }
    float4 v = ((const float4*)in)[j];
    union { uint16_t u[4]; uint64_t q; } o;
    o.u[0] = f2bf(v.x); o.u[1] = f2bf(v.y); o.u[2] = f2bf(v.z); o.u[3] = f2bf(v.w);
    ((uint64_t*)out)[j] = o.q;
    return;
  }
  id -= 10240;
  const float* W;
  uint16_t* Wt;
  int N, n0, k0;
  float sc = 1.0f;
  if (id < 1024)      { W = Wq;   Wt = wqt;   N = 1024; sc = qscale;
                        n0 = (id & 31) * 32; k0 = (id >> 5) * 32; }
  else if (id < 2048) { W = Wout; Wt = woutt; N = 1024; id -= 1024;
                        n0 = (id & 31) * 32; k0 = (id >> 5) * 32; }
  else                { W = Wkv;  Wt = wkvt;  N = 2048; id -= 2048;
                        n0 = (id & 63) * 32; k0 = (id >> 6) * 32; }
  int c = tid & 31, r0 = tid >> 5;
#pragma unroll
  for (int i = 0; i < 4; i++) {
    int r = r0 + i * 8;
    tile[r][c] = W[(size_t)(k0 + r) * N + n0 + c];
  }
  __syncthreads();
#pragma unroll
  for (int i = 0; i < 4; i++) {
    int r = r0 + i * 8;
    Wt[(size_t)(n0 + r) * 1024 + k0 + c] = f2bf(tile[c][r] * sc);
  }
}

// ---------------- fused GEMM: kv = ctx @ Wkv (K->kb, V->vtb^T) and q = x @ Wq' ----------------
// BK=64 (16 K-iters), XCD-aware swizzle: xcd=id&7 selects the A-panel group so
// the 16 col-tiles sharing a 128-row A-panel run on one XCD (A L2-resident,
// fetched once device-wide).
__global__ __launch_bounds__(256) void k_gemm_fused(const uint16_t* __restrict__ ctxb,
                                                    const uint16_t* __restrict__ wkvt,
                                                    const uint16_t* __restrict__ xb,
                                                    const uint16_t* __restrict__ wqt,
                                                    uint16_t* __restrict__ kb,
                                                    uint16_t* __restrict__ vtb,
                                                    uint16_t* __restrict__ qb) {
  __shared__ uint16_t smem[16384]; // la [0,8192), lb [8192,16384); V-epilogue reuses [0,9216)
  uint16_t* la = smem;
  uint16_t* lb = smem + 8192;
  const int K = 1024;
  const int tid = threadIdx.x;
  const int lane = tid & 63, w = tid >> 6;
  const int quad = lane >> 4, l16 = lane & 15;
  const int wr = (w >> 1) * 64, wc = (w & 1) * 64;
  int id = blockIdx.x;
  int bx, by, isQ;
  const uint16_t *Ab, *Bb;
  if (id < 1024) {
    isQ = 0;
    int xcd = id & 7, t = id >> 3;         // t in [0,128)
    by = (xcd << 3) + (t & 7);             // 8 A-panels per XCD
    bx = t >> 3;                           // all 16 col tiles on that XCD
    Ab = ctxb + (size_t)by * 128 * K;
    Bb = wkvt + (size_t)bx * 128 * K;
  } else {
    isQ = 1; id -= 1024;
    int xcd = id & 7, t = id >> 3;         // t in [0,16)
    by = (xcd << 1) + (t & 1);             // 2 A-panels per XCD
    bx = t >> 1;
    Ab = xb + (size_t)by * 128 * K;
    Bb = wqt + (size_t)bx * 128 * K;
  }
  f32x4 acc[4][4] = {};
  for (int k0 = 0; k0 < K; k0 += 64) {
    __syncthreads();
#pragma unroll
    for (int ii = 0; ii < 4; ii++) {
      int g = tid + ii * 256;
      int row = g >> 3, slot = g & 7, seg = (slot ^ (row & 7)) * 8;
      load_lds16(Ab + (size_t)row * K + k0 + seg, la + g * 8);
      load_lds16(Bb + (size_t)row * K + k0 + seg, lb + g * 8);
    }
    __syncthreads();
#pragma unroll
    for (int sub = 0; sub < 2; sub++) {
      const int kk = sub * 4 + quad;
      bf16x8 af[4], bfr[4];
#pragma unroll
      for (int i = 0; i < 4; i++) {
        int R = wr + i * 16 + l16;
        af[i] = *(const bf16x8*)&la[R * 64 + ((kk ^ (R & 7)) * 8)];
      }
#pragma unroll
      for (int j = 0; j < 4; j++) {
        int R = wc + j * 16 + l16;
        bfr[j] = *(const bf16x8*)&lb[R * 64 + ((kk ^ (R & 7)) * 8)];
      }
#pragma unroll
      for (int i = 0; i < 4; i++)
#pragma unroll
        for (int j = 0; j < 4; j++)
          acc[i][j] = __builtin_amdgcn_mfma_f32_16x16x32_bf16(af[i], bfr[j], acc[i][j], 0, 0, 0);
    }
  }
  __syncthreads();
  if (isQ) {
#pragma unroll
    for (int i = 0; i < 4; i++)
#pragma unroll
      for (int j = 0; j < 4; j++) {
        size_t row = (size_t)by * 128 + wr + i * 16 + quad * 4;
        size_t col = (size_t)bx * 128 + wc + j * 16 + l16;
#pragma unroll
        for (int r = 0; r < 4; r++)
          qb[(row + r) * 1024 + col] = f2bf(acc[i][j][r]);
      }
  } else if (bx < 8) {
#pragma unroll
    for (int i = 0; i < 4; i++)
#pragma unroll
      for (int j = 0; j < 4; j++) {
        size_t row = (size_t)by * 128 + wr + i * 16 + quad * 4;
        size_t col = (size_t)bx * 128 + wc + j * 16 + l16;
#pragma unroll
        for (int r = 0; r < 4; r++)
          kb[(row + r) * 1024 + col] = f2bf(acc[i][j][r]);
      }
  } else {
    const int bh = (by >> 5) * 8 + (bx - 8);
    const int lbase = (by & 31) * 128;
    uint16_t* vdst = vtb + (size_t)bh * 524288;
#pragma unroll
    for (int half = 0; half < 2; half++) {
      if (wr == half * 64) {
#pragma unroll
        for (int i = 0; i < 4; i++)
#pragma unroll
          for (int j = 0; j < 4; j++) {
            int rowl = i * 16 + quad * 4;
            int col = wc + j * 16 + l16;
            union { uint64_t q; uint16_t u[4]; } pk;
#pragma unroll
            for (int r = 0; r < 4; r++) pk.u[r] = f2bf(acc[i][j][r]);
            *(uint64_t*)&smem[col * 72 + rowl] = pk.q;
          }
      }
      __syncthreads();
      {
        int col = tid >> 1, rseg = (tid & 1) * 32;
        const uint16_t* src = &smem[col * 72 + rseg];
        uint16_t* d = vdst + (size_t)col * 4096 + lbase + half * 64 + rseg;
#pragma unroll
        for (int k = 0; k < 4; k++)
          ((uint4*)d)[k] = *(const uint4*)&src[k * 8];
      }
      __syncthreads();
    }
  }
}

// ---------------- GEMM 64x64 tile, BK=64 (for out) ----------------
__global__ __launch_bounds__(256) void k_gemm64(const uint16_t* __restrict__ A,
                                                const uint16_t* __restrict__ Bt,
                                                float* __restrict__ Cf,
                                                const float* __restrict__ bias,
                                                int M, int N, int K) {
  __shared__ uint16_t la[64 * 64];
  __shared__ uint16_t lb[64 * 64];
  const int tid = threadIdx.x;
  const int lane = tid & 63, w = tid >> 6;
  const int quad = lane >> 4, l16 = lane & 15;
  const int wr = (w >> 1) * 32, wc = (w & 1) * 32;
  const size_t tr0 = (size_t)blockIdx.y * 64, tc0 = (size_t)blockIdx.x * 64;
  f32x4 acc[2][2] = {};
  const int rS = tid >> 3, sS = tid & 7;
  const int seg = (sS ^ (rS & 7)) * 8;
  const uint16_t* Ab = A + tr0 * K;
  const uint16_t* Bb = Bt + tc0 * K;
  for (int k0 = 0; k0 < K; k0 += 64) {
    __syncthreads();
    load_lds16(Ab + (size_t)rS * K + k0 + seg, la + tid * 8);
    load_lds16(Ab + (size_t)(rS + 32) * K + k0 + seg, la + (tid + 256) * 8);
    load_lds16(Bb + (size_t)rS * K + k0 + seg, lb + tid * 8);
    load_lds16(Bb + (size_t)(rS + 32) * K + k0 + seg, lb + (tid + 256) * 8);
    __syncthreads();
#pragma unroll
    for (int sub = 0; sub < 2; sub++) {
      const int kk = sub * 4 + quad;
      bf16x8 af[2], bfr[2];
#pragma unroll
      for (int i = 0; i < 2; i++) {
        int R = wr + i * 16 + l16;
        af[i] = *(const bf16x8*)&la[R * 64 + (kk ^ (R & 7)) * 8];
      }
#pragma unroll
      for (int j = 0; j < 2; j++) {
        int R = wc + j * 16 + l16;
        bfr[j] = *(const bf16x8*)&lb[R * 64 + (kk ^ (R & 7)) * 8];
      }
#pragma unroll
      for (int i = 0; i < 2; i++)
#pragma unroll
        for (int j = 0; j < 2; j++)
          acc[i][j] = __builtin_amdgcn_mfma_f32_16x16x32_bf16(af[i], bfr[j], acc[i][j], 0, 0, 0);
    }
  }
#pragma unroll
  for (int i = 0; i < 2; i++) {
#pragma unroll
    for (int j = 0; j < 2; j++) {
      size_t row = tr0 + wr + i * 16 + quad * 4;
      size_t col = tc0 + wc + j * 16 + l16;
#pragma unroll
      for (int r = 0; r < 4; r++)
        Cf[(row + r) * N + col] = acc[i][j][r] + bias[col];
    }
  }
}

// ---------------- flash attention, key-split x8, merge fused (last-block-done) ----------------
// flat grid 1024: idx = qb*128 + g, g = h*16 + b*8 + sp (idx%8 = sp -> each XCD
// owns one split; the 8 q-blocks sharing a K/V slice are co-XCD; 4 MB K/V = L2).
// Per chunk: DMA-stage K/V, then per 32-key half: QK -> exp2 -> P (wave-local
// LDS) -> PV. No online max; split weight applied at epilogue; row sums via a
// register ones-fragment MFMA. After epilogue, a device-scope counter elects
// the last of each group's 8 split blocks to do the weighted-sum merge -> attb.
__global__ __launch_bounds__(256) void k_attn(const uint16_t* __restrict__ q,
                                              const uint16_t* __restrict__ kb,
                                              const uint16_t* __restrict__ vt,
                                              const float* __restrict__ sims,
                                              const float* __restrict__ beta,
                                              uint16_t* __restrict__ po,
                                              float* __restrict__ pl,
                                              uint32_t* __restrict__ cnt,
                                              uint16_t* __restrict__ attb) {
  __shared__ uint16_t Kl[8192];
  __shared__ uint16_t Vl[8192];
  __shared__ uint16_t Pl[4096];
  __shared__ int isLast;
  const int idx = blockIdx.x;
  const int qbx = idx >> 7, g = idx & 127;
  const int h = g >> 4, b = (g >> 3) & 1, sp = g & 7;
  const int q0 = qbx * 128;
  const int tid = threadIdx.x, lane = tid & 63, w = tid >> 6;
  const int quad = lane >> 4, l16 = lane & 15;
  const float wsplit =
      __builtin_amdgcn_exp2f(sims[b * 4 + (sp >> 1)] * beta[0] * 1.44269504f);
  uint16_t* Pw = Pl + w * 1024;

  union { uint32_t u[4]; bf16x8 v; } Oc;
#pragma unroll
  for (int j = 0; j < 4; j++) Oc.u[j] = 0x3F803F80u;
  const bf16x8 onesf = Oc.v;

  bf16x8 qf[2][4];
#pragma unroll
  for (int rb = 0; rb < 2; rb++) {
    const uint16_t* qrow =
        q + ((size_t)(b * 1024 + q0 + w * 32 + rb * 16 + l16)) * 1024 + h * 128 + quad * 8;
#pragma unroll
    for (int ks = 0; ks < 4; ks++) qf[rb][ks] = *(const bf16x8*)(qrow + ks * 32);
  }
  f32x4 o[2][8] = {};
  f32x4 o9[2] = {};

  const uint16_t* kptr = kb + ((size_t)(b * 4096 + sp * 512)) * 1024 + h * 128;
  const uint16_t* vptr = vt + ((size_t)(b * 8 + h) * 128) * 4096 + sp * 512;

  for (int c = 0; c < 8; c++) {
    __syncthreads();
#pragma unroll
    for (int ii = 0; ii < 4; ii++) {
      int g2 = tid + ii * 256;
      int row = g2 >> 4, seg = (g2 & 15) ^ (row & 15);
      load_lds16(kptr + (size_t)row * 1024 + seg * 8, Kl + g2 * 8);
    }
#pragma unroll
    for (int ii = 0; ii < 4; ii++) {
      int g2 = tid + ii * 256;
      int row = g2 >> 3, seg = (g2 & 7) ^ (row & 7);
      load_lds16(vptr + (size_t)row * 4096 + seg * 8, Vl + g2 * 8);
    }
    __syncthreads();
#pragma unroll
    for (int kh = 0; kh < 2; kh++) {
#pragma unroll
      for (int nb2 = 0; nb2 < 2; nb2++) {
        const int nb = kh * 2 + nb2;
        f32x4 s0 = {}, s1 = {};
#pragma unroll
        for (int ks = 0; ks < 4; ks++) {
          bf16x8 kf = *(const bf16x8*)&Kl[(nb * 16 + l16) * 128 + (((ks * 4 + quad) ^ l16) * 8)];
          s0 = __builtin_amdgcn_mfma_f32_16x16x32_bf16(qf[0][ks], kf, s0, 0, 0, 0);
          s1 = __builtin_amdgcn_mfma_f32_16x16x32_bf16(qf[1][ks], kf, s1, 0, 0, 0);
        }
        const int sl = nb2 * 2 + (l16 >> 3);
#pragma unroll
        for (int r = 0; r < 4; r++) {
          int rp0 = quad * 4 + r;
          Pw[rp0 * 32 + ((sl ^ ((rp0 >> 1) & 3)) * 8) + (l16 & 7)] =
              f2bf(__builtin_amdgcn_exp2f(s0[r]));
          int rp1 = 16 + rp0;
          Pw[rp1 * 32 + ((sl ^ ((rp1 >> 1) & 3)) * 8) + (l16 & 7)] =
              f2bf(__builtin_amdgcn_exp2f(s1[r]));
        }
      }
      __asm__ volatile("s_waitcnt lgkmcnt(0)" ::: "memory");
      const int segp = (quad ^ ((l16 >> 1) & 3)) * 8;
      bf16x8 pf0 = *(const bf16x8*)&Pw[l16 * 32 + segp];
      bf16x8 pf1 = *(const bf16x8*)&Pw[(16 + l16) * 32 + segp];
      const int sq = ((kh * 4 + quad) ^ (l16 & 7)) * 8;
#pragma unroll
      for (int nb = 0; nb < 8; nb++) {
        bf16x8 vf = *(const bf16x8*)&Vl[(nb * 16 + l16) * 64 + sq];
        o[0][nb] = __builtin_amdgcn_mfma_f32_16x16x32_bf16(pf0, vf, o[0][nb], 0, 0, 0);
        o[1][nb] = __builtin_amdgcn_mfma_f32_16x16x32_bf16(pf1, vf, o[1][nb], 0, 0, 0);
      }
      o9[0] = __builtin_amdgcn_mfma_f32_16x16x32_bf16(pf0, onesf, o9[0], 0, 0, 0);
      o9[1] = __builtin_amdgcn_mfma_f32_16x16x32_bf16(pf1, onesf, o9[1], 0, 0, 0);
    }
    kptr += (size_t)64 * 1024;
    vptr += 64;
  }
  // epilogue: sim-weighted partial O (bf16) + weighted row sums
  const int rowbase = (sp * 16 + b * 8 + h) * 1024 + q0 + w * 32;
#pragma unroll
  for (int rb = 0; rb < 2; rb++)
#pragma unroll
    for (int r = 0; r < 4; r++) {
      int row = rowbase + rb * 16 + quad * 4 + r;
#pragma unroll
      for (int nb = 0; nb < 8; nb++)
        po[(size_t)row * 128 + nb * 16 + l16] = f2bf(o[rb][nb][r] * wsplit);
      if (l16 == 0)
        pl[row] = o9[rb][r] * wsplit;
    }
  // ---- last-block-done merge for this (qbx, b, h) group ----
  __threadfence();
  if (tid == 0) {
    const int grp = (qbx << 4) + (g >> 3); // qbx*16 + h*2 + b
    isLast = (atomicAdd(&cnt[grp], 1u) == 7u) ? 1 : 0;
  }
  __syncthreads();
  if (!isLast) return;
  __threadfence(); // acquire: other splits' po/pl visible
  const int bh = b * 8 + h;
  const int qi = q0 + (tid >> 1);
  const int d0 = (tid & 1) * 64;
  float den = 0.f;
#pragma unroll
  for (int s = 0; s < 8; s++) den += pl[(s * 16 + bh) * 1024 + qi];
  const float inv = 1.0f / den;
#pragma unroll
  for (int p = 0; p < 4; p++) {
    float acc[16] = {};
#pragma unroll
    for (int s = 0; s < 8; s++) {
      const uint16_t* src =
          po + ((size_t)((s * 16 + bh) * 1024 + qi)) * 128 + d0 + p * 16;
      union { uint4 v; uint16_t u[8]; } a0, a1;
      a0.v = *(const uint4*)src;
      a1.v = *(const uint4*)(src + 8);
#pragma unroll
      for (int j = 0; j < 8; j++) { acc[j] += bf2f(a0.u[j]); acc[8 + j] += bf2f(a1.u[j]); }
    }
    union { uint4 v[2]; uint16_t u[16]; } ov;
#pragma unroll
    for (int j = 0; j < 16; j++) ov.u[j] = f2bf(acc[j] * inv);
    uint16_t* dst = attb + ((size_t)(b * 1024 + qi)) * 1024 + h * 128 + d0 + p * 16;
    *(uint4*)dst = ov.v[0];
    *(uint4*)(dst + 8) = ov.v[1];
  }
}

// ---------------- launch ----------------
extern "C" void kernel_launch(void* const* d_in, const int* in_sizes, int n_in,
                              void* d_out, int out_size, void* d_ws, size_t ws_size,
                              hipStream_t stream) {
  (void)in_sizes; (void)n_in; (void)out_size; (void)ws_size;
  const float* x    = (const float*)d_in[0];
  const float* ctx  = (const float*)d_in[1];
  const float* sims = (const float*)d_in[2];
  const float* Wq   = (const float*)d_in[3];
  const float* Wkv  = (const float*)d_in[4];
  const float* beta = (const float*)d_in[5];
  const float* Wout = (const float*)d_in[6];
  const float* bout = (const float*)d_in[7];
  float* out = (float*)d_out;

  char* ws = (char*)d_ws;
  uint16_t* xb    = (uint16_t*)(ws + 0);           // 4 MB  (dead after fused GEMM)
  uint16_t* ctxb  = (uint16_t*)(ws + (4u << 20));  // 16 MB (dead after fused GEMM)
  uint16_t* wqt   = (uint16_t*)(ws + (20u << 20)); // 2 MB  (dead after fused GEMM)
  uint16_t* wkvt  = (uint16_t*)(ws + (22u << 20)); // 4 MB  (dead after fused GEMM)
  uint16_t* kb    = (uint16_t*)(ws + (32u << 20)); // 16 MB [8192][1024]
  uint16_t* vtb   = (uint16_t*)(ws + (48u << 20)); // 16 MB [16][128][4096]
  float*    pl    = (float*)   (ws + (64u << 20)); // 512 KB [128][1024]
  uint32_t* cnt   = (uint32_t*)(ws + (65u << 20)); // 512 B  [128]
  uint16_t* woutt = (uint16_t*)(ws + (68u << 20)); // 2 MB (live till end)
  uint16_t* qb    = (uint16_t*)(ws + (70u << 20)); // 4 MB (live till attn)
  uint16_t* attb  = (uint16_t*)(ws + (74u << 20)); // 4 MB
  uint16_t* po    = (uint16_t*)(ws + 0);           // 32 MB, reuses 0..32 MB

  const float LOG2E = 1.44269504f;
  const float qscale = 0.03125f * LOG2E;

  hipMemsetAsync(cnt, 0, 128 * sizeof(uint32_t), stream);
  k_prep<<<14336, 256, 0, stream>>>(x, ctx, Wq, Wkv, Wout, xb, ctxb, wqt, wkvt, woutt, qscale);
  k_gemm_fused<<<1152, 256, 0, stream>>>(ctxb, wkvt, xb, wqt, kb, vtb, qb);
  k_attn<<<1024, 256, 0, stream>>>(qb, kb, vtb, sims, beta, po, pl, cnt, attb);
  k_gemm64<<<dim3(16, 32), 256, 0, stream>>>(attb, woutt, out, bout, 2048, 1024, 1024);
}

// Round 9
// 238.727 us; speedup vs baseline: 2.0787x; 2.0787x over previous
//
#include <hip/hip_runtime.h>
#include <stdint.h>

typedef __attribute__((ext_vector_type(4))) float f32x4;
typedef __attribute__((ext_vector_type(8))) __bf16 bf16x8;

__device__ __forceinline__ uint16_t f2bf(float f) {
  uint32_t u = __builtin_bit_cast(uint32_t, f);
  u += 0x7FFFu + ((u >> 16) & 1u);
  return (uint16_t)(u >> 16);
}

__device__ __forceinline__ float bf2f(uint16_t u) {
  uint32_t v = ((uint32_t)u) << 16;
  return __builtin_bit_cast(float, v);
}

__device__ __forceinline__ void load_lds16(const uint16_t* g, uint16_t* l) {
  __builtin_amdgcn_global_load_lds((const __attribute__((address_space(1))) void*)g,
                                   (__attribute__((address_space(3))) void*)l, 16, 0, 0);
}

// ---------------- fused prep: convert x+ctx to bf16, transpose 3 W's ----------------
__global__ __launch_bounds__(256) void k_prep(const float* __restrict__ x,
                                              const float* __restrict__ ctx,
                                              const float* __restrict__ Wq,
                                              const float* __restrict__ Wkv,
                                              const float* __restrict__ Wout,
                                              uint16_t* __restrict__ xb,
                                              uint16_t* __restrict__ ctxb,
                                              uint16_t* __restrict__ wqt,
                                              uint16_t* __restrict__ wkvt,
                                              uint16_t* __restrict__ woutt,
                                              float qscale) {
  __shared__ float tile[32][33];
  int id = blockIdx.x;
  int tid = threadIdx.x;
  if (id < 10240) {
    const float* in;
    uint16_t* out;
    int j = id * 256 + tid;
    if (j < 524288) { in = x; out = xb; }
    else            { in = ctx; out = ctxb; j -= 524288; }
    float4 v = ((const float4*)in)[j];
    union { uint16_t u[4]; uint64_t q; } o;
    o.u[0] = f2bf(v.x); o.u[1] = f2bf(v.y); o.u[2] = f2bf(v.z); o.u[3] = f2bf(v.w);
    ((uint64_t*)out)[j] = o.q;
    return;
  }
  id -= 10240;
  const float* W;
  uint16_t* Wt;
  int N, n0, k0;
  float sc = 1.0f;
  if (id < 1024)      { W = Wq;   Wt = wqt;   N = 1024; sc = qscale;
                        n0 = (id & 31) * 32; k0 = (id >> 5) * 32; }
  else if (id < 2048) { W = Wout; Wt = woutt; N = 1024; id -= 1024;
                        n0 = (id & 31) * 32; k0 = (id >> 5) * 32; }
  else                { W = Wkv;  Wt = wkvt;  N = 2048; id -= 2048;
                        n0 = (id & 63) * 32; k0 = (id >> 6) * 32; }
  int c = tid & 31, r0 = tid >> 5;
#pragma unroll
  for (int i = 0; i < 4; i++) {
    int r = r0 + i * 8;
    tile[r][c] = W[(size_t)(k0 + r) * N + n0 + c];
  }
  __syncthreads();
#pragma unroll
  for (int i = 0; i < 4; i++) {
    int r = r0 + i * 8;
    Wt[(size_t)(n0 + r) * 1024 + k0 + c] = f2bf(tile[c][r] * sc);
  }
}

// ---------------- fused GEMM: kv = ctx @ Wkv (K->kb, V->vtb^T) and q = x @ Wq' ----------------
// BK=64 (16 K-iters), XCD-aware swizzle: xcd=id&7 selects the A-panel group so
// the 16 col-tiles sharing a 128-row A-panel run on one XCD (A L2-resident).
__global__ __launch_bounds__(256) void k_gemm_fused(const uint16_t* __restrict__ ctxb,
                                                    const uint16_t* __restrict__ wkvt,
                                                    const uint16_t* __restrict__ xb,
                                                    const uint16_t* __restrict__ wqt,
                                                    uint16_t* __restrict__ kb,
                                                    uint16_t* __restrict__ vtb,
                                                    uint16_t* __restrict__ qb) {
  __shared__ uint16_t smem[16384]; // la [0,8192), lb [8192,16384); V-epilogue reuses [0,9216)
  uint16_t* la = smem;
  uint16_t* lb = smem + 8192;
  const int K = 1024;
  const int tid = threadIdx.x;
  const int lane = tid & 63, w = tid >> 6;
  const int quad = lane >> 4, l16 = lane & 15;
  const int wr = (w >> 1) * 64, wc = (w & 1) * 64;
  int id = blockIdx.x;
  int bx, by, isQ;
  const uint16_t *Ab, *Bb;
  if (id < 1024) {
    isQ = 0;
    int xcd = id & 7, t = id >> 3;         // t in [0,128)
    by = (xcd << 3) + (t & 7);             // 8 A-panels per XCD
    bx = t >> 3;                           // all 16 col tiles on that XCD
    Ab = ctxb + (size_t)by * 128 * K;
    Bb = wkvt + (size_t)bx * 128 * K;
  } else {
    isQ = 1; id -= 1024;
    int xcd = id & 7, t = id >> 3;         // t in [0,16)
    by = (xcd << 1) + (t & 1);             // 2 A-panels per XCD
    bx = t >> 1;
    Ab = xb + (size_t)by * 128 * K;
    Bb = wqt + (size_t)bx * 128 * K;
  }
  f32x4 acc[4][4] = {};
  for (int k0 = 0; k0 < K; k0 += 64) {
    __syncthreads();
#pragma unroll
    for (int ii = 0; ii < 4; ii++) {
      int g = tid + ii * 256;
      int row = g >> 3, slot = g & 7, seg = (slot ^ (row & 7)) * 8;
      load_lds16(Ab + (size_t)row * K + k0 + seg, la + g * 8);
      load_lds16(Bb + (size_t)row * K + k0 + seg, lb + g * 8);
    }
    __syncthreads();
#pragma unroll
    for (int sub = 0; sub < 2; sub++) {
      const int kk = sub * 4 + quad;
      bf16x8 af[4], bfr[4];
#pragma unroll
      for (int i = 0; i < 4; i++) {
        int R = wr + i * 16 + l16;
        af[i] = *(const bf16x8*)&la[R * 64 + ((kk ^ (R & 7)) * 8)];
      }
#pragma unroll
      for (int j = 0; j < 4; j++) {
        int R = wc + j * 16 + l16;
        bfr[j] = *(const bf16x8*)&lb[R * 64 + ((kk ^ (R & 7)) * 8)];
      }
#pragma unroll
      for (int i = 0; i < 4; i++)
#pragma unroll
        for (int j = 0; j < 4; j++)
          acc[i][j] = __builtin_amdgcn_mfma_f32_16x16x32_bf16(af[i], bfr[j], acc[i][j], 0, 0, 0);
    }
  }
  __syncthreads();
  if (isQ) {
#pragma unroll
    for (int i = 0; i < 4; i++)
#pragma unroll
      for (int j = 0; j < 4; j++) {
        size_t row = (size_t)by * 128 + wr + i * 16 + quad * 4;
        size_t col = (size_t)bx * 128 + wc + j * 16 + l16;
#pragma unroll
        for (int r = 0; r < 4; r++)
          qb[(row + r) * 1024 + col] = f2bf(acc[i][j][r]);
      }
  } else if (bx < 8) {
#pragma unroll
    for (int i = 0; i < 4; i++)
#pragma unroll
      for (int j = 0; j < 4; j++) {
        size_t row = (size_t)by * 128 + wr + i * 16 + quad * 4;
        size_t col = (size_t)bx * 128 + wc + j * 16 + l16;
#pragma unroll
        for (int r = 0; r < 4; r++)
          kb[(row + r) * 1024 + col] = f2bf(acc[i][j][r]);
      }
  } else {
    const int bh = (by >> 5) * 8 + (bx - 8);
    const int lbase = (by & 31) * 128;
    uint16_t* vdst = vtb + (size_t)bh * 524288;
#pragma unroll
    for (int half = 0; half < 2; half++) {
      if (wr == half * 64) {
#pragma unroll
        for (int i = 0; i < 4; i++)
#pragma unroll
          for (int j = 0; j < 4; j++) {
            int rowl = i * 16 + quad * 4;
            int col = wc + j * 16 + l16;
            union { uint64_t q; uint16_t u[4]; } pk;
#pragma unroll
            for (int r = 0; r < 4; r++) pk.u[r] = f2bf(acc[i][j][r]);
            *(uint64_t*)&smem[col * 72 + rowl] = pk.q;
          }
      }
      __syncthreads();
      {
        int col = tid >> 1, rseg = (tid & 1) * 32;
        const uint16_t* src = &smem[col * 72 + rseg];
        uint16_t* d = vdst + (size_t)col * 4096 + lbase + half * 64 + rseg;
#pragma unroll
        for (int k = 0; k < 4; k++)
          ((uint4*)d)[k] = *(const uint4*)&src[k * 8];
      }
      __syncthreads();
    }
  }
}

// ---------------- GEMM 64x64 tile, BK=64 (for out) ----------------
__global__ __launch_bounds__(256) void k_gemm64(const uint16_t* __restrict__ A,
                                                const uint16_t* __restrict__ Bt,
                                                float* __restrict__ Cf,
                                                const float* __restrict__ bias,
                                                int M, int N, int K) {
  __shared__ uint16_t la[64 * 64];
  __shared__ uint16_t lb[64 * 64];
  const int tid = threadIdx.x;
  const int lane = tid & 63, w = tid >> 6;
  const int quad = lane >> 4, l16 = lane & 15;
  const int wr = (w >> 1) * 32, wc = (w & 1) * 32;
  const size_t tr0 = (size_t)blockIdx.y * 64, tc0 = (size_t)blockIdx.x * 64;
  f32x4 acc[2][2] = {};
  const int rS = tid >> 3, sS = tid & 7;
  const int seg = (sS ^ (rS & 7)) * 8;
  const uint16_t* Ab = A + tr0 * K;
  const uint16_t* Bb = Bt + tc0 * K;
  for (int k0 = 0; k0 < K; k0 += 64) {
    __syncthreads();
    load_lds16(Ab + (size_t)rS * K + k0 + seg, la + tid * 8);
    load_lds16(Ab + (size_t)(rS + 32) * K + k0 + seg, la + (tid + 256) * 8);
    load_lds16(Bb + (size_t)rS * K + k0 + seg, lb + tid * 8);
    load_lds16(Bb + (size_t)(rS + 32) * K + k0 + seg, lb + (tid + 256) * 8);
    __syncthreads();
#pragma unroll
    for (int sub = 0; sub < 2; sub++) {
      const int kk = sub * 4 + quad;
      bf16x8 af[2], bfr[2];
#pragma unroll
      for (int i = 0; i < 2; i++) {
        int R = wr + i * 16 + l16;
        af[i] = *(const bf16x8*)&la[R * 64 + (kk ^ (R & 7)) * 8];
      }
#pragma unroll
      for (int j = 0; j < 2; j++) {
        int R = wc + j * 16 + l16;
        bfr[j] = *(const bf16x8*)&lb[R * 64 + (kk ^ (R & 7)) * 8];
      }
#pragma unroll
      for (int i = 0; i < 2; i++)
#pragma unroll
        for (int j = 0; j < 2; j++)
          acc[i][j] = __builtin_amdgcn_mfma_f32_16x16x32_bf16(af[i], bfr[j], acc[i][j], 0, 0, 0);
    }
  }
#pragma unroll
  for (int i = 0; i < 2; i++) {
#pragma unroll
    for (int j = 0; j < 2; j++) {
      size_t row = tr0 + wr + i * 16 + quad * 4;
      size_t col = tc0 + wc + j * 16 + l16;
#pragma unroll
      for (int r = 0; r < 4; r++)
        Cf[(row + r) * N + col] = acc[i][j][r] + bias[col];
    }
  }
}

// ---------------- flash attention, key-split x8, 40 KB LDS, 4 blocks/CU ----------------
// (R7 structure: separate merge launch. In-kernel cross-XCD merge was a 10x
// regression — device-scope __threadfence forces L2 writeback of the 32 MB po,
// defeating cache-resident handoff. Kernel boundary gives ordering for free.)
__global__ __launch_bounds__(256) void k_attn(const uint16_t* __restrict__ q,
                                              const uint16_t* __restrict__ kb,
                                              const uint16_t* __restrict__ vt,
                                              const float* __restrict__ sims,
                                              const float* __restrict__ beta,
                                              uint16_t* __restrict__ po,
                                              float* __restrict__ pl) {
  __shared__ uint16_t Kl[8192];   // 64 keys x 128 hd, seg-swizzled (16 KB)
  __shared__ uint16_t Vl[8192];   // 128 d x 64 keys, seg-swizzled (16 KB)
  __shared__ uint16_t Pl[4096];   // 4 waves x 32 rows x 32 keys (8 KB)
  const int idx = blockIdx.x;
  const int qbx = idx >> 7, g = idx & 127;
  const int h = g >> 4, b = (g >> 3) & 1, sp = g & 7;
  const int q0 = qbx * 128;
  const int tid = threadIdx.x, lane = tid & 63, w = tid >> 6;
  const int quad = lane >> 4, l16 = lane & 15;
  const float wsplit =
      __builtin_amdgcn_exp2f(sims[b * 4 + (sp >> 1)] * beta[0] * 1.44269504f);
  uint16_t* Pw = Pl + w * 1024;

  union { uint32_t u[4]; bf16x8 v; } Oc;
#pragma unroll
  for (int j = 0; j < 4; j++) Oc.u[j] = 0x3F803F80u;
  const bf16x8 onesf = Oc.v;

  bf16x8 qf[2][4];
#pragma unroll
  for (int rb = 0; rb < 2; rb++) {
    const uint16_t* qrow =
        q + ((size_t)(b * 1024 + q0 + w * 32 + rb * 16 + l16)) * 1024 + h * 128 + quad * 8;
#pragma unroll
    for (int ks = 0; ks < 4; ks++) qf[rb][ks] = *(const bf16x8*)(qrow + ks * 32);
  }
  f32x4 o[2][8] = {};
  f32x4 o9[2] = {};

  const uint16_t* kptr = kb + ((size_t)(b * 4096 + sp * 512)) * 1024 + h * 128;
  const uint16_t* vptr = vt + ((size_t)(b * 8 + h) * 128) * 4096 + sp * 512;

  for (int c = 0; c < 8; c++) {
    __syncthreads(); // prev chunk's frag reads done before restage
#pragma unroll
    for (int ii = 0; ii < 4; ii++) {
      int g2 = tid + ii * 256;
      int row = g2 >> 4, seg = (g2 & 15) ^ (row & 15);
      load_lds16(kptr + (size_t)row * 1024 + seg * 8, Kl + g2 * 8);
    }
#pragma unroll
    for (int ii = 0; ii < 4; ii++) {
      int g2 = tid + ii * 256;
      int row = g2 >> 3, seg = (g2 & 7) ^ (row & 7);
      load_lds16(vptr + (size_t)row * 4096 + seg * 8, Vl + g2 * 8);
    }
    __syncthreads(); // DMA complete
#pragma unroll
    for (int kh = 0; kh < 2; kh++) {
      // QK for this 32-key half; exp2 + P-half spill fused
#pragma unroll
      for (int nb2 = 0; nb2 < 2; nb2++) {
        const int nb = kh * 2 + nb2;
        f32x4 s0 = {}, s1 = {};
#pragma unroll
        for (int ks = 0; ks < 4; ks++) {
          bf16x8 kf = *(const bf16x8*)&Kl[(nb * 16 + l16) * 128 + (((ks * 4 + quad) ^ l16) * 8)];
          s0 = __builtin_amdgcn_mfma_f32_16x16x32_bf16(qf[0][ks], kf, s0, 0, 0, 0);
          s1 = __builtin_amdgcn_mfma_f32_16x16x32_bf16(qf[1][ks], kf, s1, 0, 0, 0);
        }
        const int sl = nb2 * 2 + (l16 >> 3); // key seg within the half (0..3)
#pragma unroll
        for (int r = 0; r < 4; r++) {
          int rp0 = quad * 4 + r;
          Pw[rp0 * 32 + ((sl ^ ((rp0 >> 1) & 3)) * 8) + (l16 & 7)] =
              f2bf(__builtin_amdgcn_exp2f(s0[r]));
          int rp1 = 16 + rp0;
          Pw[rp1 * 32 + ((sl ^ ((rp1 >> 1) & 3)) * 8) + (l16 & 7)] =
              f2bf(__builtin_amdgcn_exp2f(s1[r]));
        }
      }
      __asm__ volatile("s_waitcnt lgkmcnt(0)" ::: "memory"); // wave-local P visibility
      // PV for this half
      const int segp = (quad ^ ((l16 >> 1) & 3)) * 8;
      bf16x8 pf0 = *(const bf16x8*)&Pw[l16 * 32 + segp];
      bf16x8 pf1 = *(const bf16x8*)&Pw[(16 + l16) * 32 + segp];
      const int sq = ((kh * 4 + quad) ^ (l16 & 7)) * 8;
#pragma unroll
      for (int nb = 0; nb < 8; nb++) {
        bf16x8 vf = *(const bf16x8*)&Vl[(nb * 16 + l16) * 64 + sq];
        o[0][nb] = __builtin_amdgcn_mfma_f32_16x16x32_bf16(pf0, vf, o[0][nb], 0, 0, 0);
        o[1][nb] = __builtin_amdgcn_mfma_f32_16x16x32_bf16(pf1, vf, o[1][nb], 0, 0, 0);
      }
      o9[0] = __builtin_amdgcn_mfma_f32_16x16x32_bf16(pf0, onesf, o9[0], 0, 0, 0);
      o9[1] = __builtin_amdgcn_mfma_f32_16x16x32_bf16(pf1, onesf, o9[1], 0, 0, 0);
    }
    kptr += (size_t)64 * 1024;
    vptr += 64;
  }
  // epilogue: sim-weighted partial O (bf16) + weighted row sums
  const int rowbase = (sp * 16 + b * 8 + h) * 1024 + q0 + w * 32;
#pragma unroll
  for (int rb = 0; rb < 2; rb++)
#pragma unroll
    for (int r = 0; r < 4; r++) {
      int row = rowbase + rb * 16 + quad * 4 + r;
#pragma unroll
      for (int nb = 0; nb < 8; nb++)
        po[(size_t)row * 128 + nb * 16 + l16] = f2bf(o[rb][nb][r] * wsplit);
      if (l16 == 0)
        pl[row] = o9[rb][r] * wsplit;
    }
}

// ---------------- merge 8 key-split partials (plain weighted sum) -> attb ----------------
__global__ __launch_bounds__(256) void k_merge(const uint16_t* __restrict__ po,
                                               const float* __restrict__ pl,
                                               uint16_t* __restrict__ attb) {
  const int bq = blockIdx.x;
  const int b = bq >> 10, qi = bq & 1023;
  const int t = threadIdx.x;
  const int h = t >> 5, d0 = (t & 31) * 4;
  const int bh = b * 8 + h;
  float den = 0.f;
  float acc[4] = {0.f, 0.f, 0.f, 0.f};
#pragma unroll
  for (int s = 0; s < 8; s++) {
    den += pl[(s * 16 + bh) * 1024 + qi];
    union { uint64_t q; uint16_t u[4]; } v;
    v.q = *(const uint64_t*)&po[(((size_t)(s * 16 + bh)) * 1024 + qi) * 128 + d0];
#pragma unroll
    for (int j = 0; j < 4; j++) acc[j] += bf2f(v.u[j]);
  }
  const float inv = 1.0f / den;
  union { uint64_t q; uint16_t u[4]; } o;
#pragma unroll
  for (int j = 0; j < 4; j++) o.u[j] = f2bf(acc[j] * inv);
  *(uint64_t*)&attb[((size_t)(b * 1024 + qi)) * 1024 + h * 128 + d0] = o.q;
}

// ---------------- launch ----------------
extern "C" void kernel_launch(void* const* d_in, const int* in_sizes, int n_in,
                              void* d_out, int out_size, void* d_ws, size_t ws_size,
                              hipStream_t stream) {
  (void)in_sizes; (void)n_in; (void)out_size; (void)ws_size;
  const float* x    = (const float*)d_in[0];
  const float* ctx  = (const float*)d_in[1];
  const float* sims = (const float*)d_in[2];
  const float* Wq   = (const float*)d_in[3];
  const float* Wkv  = (const float*)d_in[4];
  const float* beta = (const float*)d_in[5];
  const float* Wout = (const float*)d_in[6];
  const float* bout = (const float*)d_in[7];
  float* out = (float*)d_out;

  char* ws = (char*)d_ws;
  uint16_t* xb    = (uint16_t*)(ws + 0);           // 4 MB  (dead after fused GEMM)
  uint16_t* ctxb  = (uint16_t*)(ws + (4u << 20));  // 16 MB (dead after fused GEMM)
  uint16_t* wqt   = (uint16_t*)(ws + (20u << 20)); // 2 MB  (dead after fused GEMM)
  uint16_t* wkvt  = (uint16_t*)(ws + (22u << 20)); // 4 MB  (dead after fused GEMM)
  uint16_t* kb    = (uint16_t*)(ws + (32u << 20)); // 16 MB [8192][1024]
  uint16_t* vtb   = (uint16_t*)(ws + (48u << 20)); // 16 MB [16][128][4096]
  float*    pl    = (float*)   (ws + (64u << 20)); // 512 KB [128][1024]
  uint16_t* woutt = (uint16_t*)(ws + (68u << 20)); // 2 MB (live till end)
  uint16_t* qb    = (uint16_t*)(ws + (70u << 20)); // 4 MB (live till attn)
  uint16_t* attb  = (uint16_t*)(ws + (74u << 20)); // 4 MB
  // po (32 MB) reuses 0..32 MB: xb/ctxb/wqt/wkvt all dead by attention time
  uint16_t* po = (uint16_t*)(ws + 0);              // 32 MB [128][1024][128]

  const float LOG2E = 1.44269504f;
  const float qscale = 0.03125f * LOG2E;

  k_prep<<<14336, 256, 0, stream>>>(x, ctx, Wq, Wkv, Wout, xb, ctxb, wqt, wkvt, woutt, qscale);
  k_gemm_fused<<<1152, 256, 0, stream>>>(ctxb, wkvt, xb, wqt, kb, vtb, qb);
  k_attn<<<1024, 256, 0, stream>>>(qb, kb, vtb, sims, beta, po, pl);
  k_merge<<<2048, 256, 0, stream>>>(po, pl, attb);
  k_gemm64<<<dim3(16, 32), 256, 0, stream>>>(attb, woutt, out, bout, 2048, 1024, 1024);
}

// Round 10
// 229.306 us; speedup vs baseline: 2.1641x; 1.0411x over previous
//
#include <hip/hip_runtime.h>
#include <stdint.h>

typedef __attribute__((ext_vector_type(4))) float f32x4;
typedef __attribute__((ext_vector_type(8))) __bf16 bf16x8;

__device__ __forceinline__ uint16_t f2bf(float f) {
  uint32_t u = __builtin_bit_cast(uint32_t, f);
  u += 0x7FFFu + ((u >> 16) & 1u);
  return (uint16_t)(u >> 16);
}

__device__ __forceinline__ float bf2f(uint16_t u) {
  uint32_t v = ((uint32_t)u) << 16;
  return __builtin_bit_cast(float, v);
}

__device__ __forceinline__ void load_lds16(const uint16_t* g, uint16_t* l) {
  __builtin_amdgcn_global_load_lds((const __attribute__((address_space(1))) void*)g,
                                   (__attribute__((address_space(3))) void*)l, 16, 0, 0);
}

// ---------------- fused prep: convert x+ctx to bf16, transpose 3 W's ----------------
__global__ __launch_bounds__(256) void k_prep(const float* __restrict__ x,
                                              const float* __restrict__ ctx,
                                              const float* __restrict__ Wq,
                                              const float* __restrict__ Wkv,
                                              const float* __restrict__ Wout,
                                              uint16_t* __restrict__ xb,
                                              uint16_t* __restrict__ ctxb,
                                              uint16_t* __restrict__ wqt,
                                              uint16_t* __restrict__ wkvt,
                                              uint16_t* __restrict__ woutt,
                                              float qscale) {
  __shared__ float tile[32][33];
  int id = blockIdx.x;
  int tid = threadIdx.x;
  if (id < 10240) {
    const float* in;
    uint16_t* out;
    int j = id * 256 + tid;
    if (j < 524288) { in = x; out = xb; }
    else            { in = ctx; out = ctxb; j -= 524288; }
    float4 v = ((const float4*)in)[j];
    union { uint16_t u[4]; uint64_t q; } o;
    o.u[0] = f2bf(v.x); o.u[1] = f2bf(v.y); o.u[2] = f2bf(v.z); o.u[3] = f2bf(v.w);
    ((uint64_t*)out)[j] = o.q;
    return;
  }
  id -= 10240;
  const float* W;
  uint16_t* Wt;
  int N, n0, k0;
  float sc = 1.0f;
  if (id < 1024)      { W = Wq;   Wt = wqt;   N = 1024; sc = qscale;
                        n0 = (id & 31) * 32; k0 = (id >> 5) * 32; }
  else if (id < 2048) { W = Wout; Wt = woutt; N = 1024; id -= 1024;
                        n0 = (id & 31) * 32; k0 = (id >> 5) * 32; }
  else                { W = Wkv;  Wt = wkvt;  N = 2048; id -= 2048;
                        n0 = (id & 63) * 32; k0 = (id >> 6) * 32; }
  int c = tid & 31, r0 = tid >> 5;
#pragma unroll
  for (int i = 0; i < 4; i++) {
    int r = r0 + i * 8;
    tile[r][c] = W[(size_t)(k0 + r) * N + n0 + c];
  }
  __syncthreads();
#pragma unroll
  for (int i = 0; i < 4; i++) {
    int r = r0 + i * 8;
    Wt[(size_t)(n0 + r) * 1024 + k0 + c] = f2bf(tile[c][r] * sc);
  }
}

// ---------------- fused GEMM: kv = ctx @ Wkv (K->kb head-major, V->vtb^T) and q = x @ Wq' ----------------
// R7 inner loop (BK=32, hoisted swizzled addresses) + XCD A-panel swizzle:
// xcd=id&7 selects the A-panel group so all 16 col-tiles sharing a 128-row
// A-panel run on one XCD (panel fetched once, L2-resident -> barrier drains
// wait on L2 not HBM). K columns tile bx == head bx -> kb stored [b][h][l][128].
__global__ __launch_bounds__(256) void k_gemm_fused(const uint16_t* __restrict__ ctxb,
                                                    const uint16_t* __restrict__ wkvt,
                                                    const uint16_t* __restrict__ xb,
                                                    const uint16_t* __restrict__ wqt,
                                                    uint16_t* __restrict__ kb,
                                                    uint16_t* __restrict__ vtb,
                                                    uint16_t* __restrict__ qb) {
  __shared__ uint16_t smem[9216]; // loop: la=[0,4096), lb=[4096,8192); V-epilogue: [0,9216)
  uint16_t* la = smem;
  uint16_t* lb = smem + 4096;
  const int K = 1024;
  const int tid = threadIdx.x;
  const int lane = tid & 63, w = tid >> 6;
  const int quad = lane >> 4, l16 = lane & 15;
  const int wr = (w >> 1) * 64, wc = (w & 1) * 64;
  int id = blockIdx.x;
  int bx, by, isQ;
  const uint16_t *Ab, *Bb;
  if (id < 1024) {
    isQ = 0;
    int xcd = id & 7, t = id >> 3;         // t in [0,128)
    by = (xcd << 3) + (t & 7);             // 8 A-panels per XCD
    bx = t >> 3;                           // all 16 col tiles co-XCD
    Ab = ctxb + (size_t)by * 128 * K;
    Bb = wkvt + (size_t)bx * 128 * K;
  } else {
    isQ = 1; id -= 1024;
    int xcd = id & 7, t = id >> 3;         // t in [0,16)
    by = (xcd << 1) + (t & 1);             // 2 A-panels per XCD
    bx = t >> 1;
    Ab = xb + (size_t)by * 128 * K;
    Bb = wqt + (size_t)bx * 128 * K;
  }
  f32x4 acc[4][4] = {};
  const int rA = tid >> 2, slotA = tid & 3;
  const int rA1 = rA + 64;
  const int segA0 = (slotA ^ ((rA + (rA >> 2)) & 3)) * 8;
  const int segA1 = (slotA ^ ((rA1 + (rA1 >> 2)) & 3)) * 8;
  for (int k0 = 0; k0 < K; k0 += 32) {
    __syncthreads();
    load_lds16(Ab + (size_t)rA * K + k0 + segA0, la + tid * 8);
    load_lds16(Ab + (size_t)rA1 * K + k0 + segA1, la + (tid + 256) * 8);
    load_lds16(Bb + (size_t)rA * K + k0 + segA0, lb + tid * 8);
    load_lds16(Bb + (size_t)rA1 * K + k0 + segA1, lb + (tid + 256) * 8);
    __syncthreads();
    bf16x8 af[4], bfr[4];
#pragma unroll
    for (int i = 0; i < 4; i++) {
      int R = wr + i * 16 + l16;
      int s = quad ^ ((R + (R >> 2)) & 3);
      af[i] = *(const bf16x8*)&la[R * 32 + s * 8];
    }
#pragma unroll
    for (int j = 0; j < 4; j++) {
      int R = wc + j * 16 + l16;
      int s = quad ^ ((R + (R >> 2)) & 3);
      bfr[j] = *(const bf16x8*)&lb[R * 32 + s * 8];
    }
#pragma unroll
    for (int i = 0; i < 4; i++)
#pragma unroll
      for (int j = 0; j < 4; j++)
        acc[i][j] = __builtin_amdgcn_mfma_f32_16x16x32_bf16(af[i], bfr[j], acc[i][j], 0, 0, 0);
  }
  __syncthreads();
  if (isQ) {
#pragma unroll
    for (int i = 0; i < 4; i++)
#pragma unroll
      for (int j = 0; j < 4; j++) {
        size_t row = (size_t)by * 128 + wr + i * 16 + quad * 4;
        size_t col = (size_t)bx * 128 + wc + j * 16 + l16;
#pragma unroll
        for (int r = 0; r < 4; r++)
          qb[(row + r) * 1024 + col] = f2bf(acc[i][j][r]);
      }
  } else if (bx < 8) {
    // K region: head-major kb[b][h=bx][l][128]
#pragma unroll
    for (int i = 0; i < 4; i++)
#pragma unroll
      for (int j = 0; j < 4; j++) {
        int rowg = by * 128 + wr + i * 16 + quad * 4; // global ctx row
        int bb = rowg >> 12, l = rowg & 4095;
        int c = wc + j * 16 + l16;
        uint16_t* dst = kb + (((size_t)(bb * 8 + bx) * 4096 + l) * 128 + c);
#pragma unroll
        for (int r = 0; r < 4; r++)
          dst[r * 128] = f2bf(acc[i][j][r]);
      }
  } else {
    // V region: tile = head (bx-8); bounce col-major through LDS, wide stores
    const int bh = (by >> 5) * 8 + (bx - 8);
    const int lbase = (by & 31) * 128;
    uint16_t* vdst = vtb + (size_t)bh * 524288;
#pragma unroll
    for (int half = 0; half < 2; half++) {
      if (wr == half * 64) {
#pragma unroll
        for (int i = 0; i < 4; i++)
#pragma unroll
          for (int j = 0; j < 4; j++) {
            int rowl = i * 16 + quad * 4;
            int col = wc + j * 16 + l16;
            union { uint64_t q; uint16_t u[4]; } pk;
#pragma unroll
            for (int r = 0; r < 4; r++) pk.u[r] = f2bf(acc[i][j][r]);
            *(uint64_t*)&smem[col * 72 + rowl] = pk.q;
          }
      }
      __syncthreads();
      {
        int col = tid >> 1, rseg = (tid & 1) * 32;
        const uint16_t* src = &smem[col * 72 + rseg];
        uint16_t* d = vdst + (size_t)col * 4096 + lbase + half * 64 + rseg;
#pragma unroll
        for (int k = 0; k < 4; k++)
          ((uint4*)d)[k] = *(const uint4*)&src[k * 8];
      }
      __syncthreads();
    }
  }
}

// ---------------- GEMM 64x64 tile, BK=64 (for out) ----------------
__global__ __launch_bounds__(256) void k_gemm64(const uint16_t* __restrict__ A,
                                                const uint16_t* __restrict__ Bt,
                                                float* __restrict__ Cf,
                                                const float* __restrict__ bias,
                                                int M, int N, int K) {
  __shared__ uint16_t la[64 * 64];
  __shared__ uint16_t lb[64 * 64];
  const int tid = threadIdx.x;
  const int lane = tid & 63, w = tid >> 6;
  const int quad = lane >> 4, l16 = lane & 15;
  const int wr = (w >> 1) * 32, wc = (w & 1) * 32;
  const size_t tr0 = (size_t)blockIdx.y * 64, tc0 = (size_t)blockIdx.x * 64;
  f32x4 acc[2][2] = {};
  const int rS = tid >> 3, sS = tid & 7;
  const int seg = (sS ^ (rS & 7)) * 8;
  const uint16_t* Ab = A + tr0 * K;
  const uint16_t* Bb = Bt + tc0 * K;
  for (int k0 = 0; k0 < K; k0 += 64) {
    __syncthreads();
    load_lds16(Ab + (size_t)rS * K + k0 + seg, la + tid * 8);
    load_lds16(Ab + (size_t)(rS + 32) * K + k0 + seg, la + (tid + 256) * 8);
    load_lds16(Bb + (size_t)rS * K + k0 + seg, lb + tid * 8);
    load_lds16(Bb + (size_t)(rS + 32) * K + k0 + seg, lb + (tid + 256) * 8);
    __syncthreads();
#pragma unroll
    for (int sub = 0; sub < 2; sub++) {
      const int kk = sub * 4 + quad;
      bf16x8 af[2], bfr[2];
#pragma unroll
      for (int i = 0; i < 2; i++) {
        int R = wr + i * 16 + l16;
        af[i] = *(const bf16x8*)&la[R * 64 + (kk ^ (R & 7)) * 8];
      }
#pragma unroll
      for (int j = 0; j < 2; j++) {
        int R = wc + j * 16 + l16;
        bfr[j] = *(const bf16x8*)&lb[R * 64 + (kk ^ (R & 7)) * 8];
      }
#pragma unroll
      for (int i = 0; i < 2; i++)
#pragma unroll
        for (int j = 0; j < 2; j++)
          acc[i][j] = __builtin_amdgcn_mfma_f32_16x16x32_bf16(af[i], bfr[j], acc[i][j], 0, 0, 0);
    }
  }
#pragma unroll
  for (int i = 0; i < 2; i++) {
#pragma unroll
    for (int j = 0; j < 2; j++) {
      size_t row = tr0 + wr + i * 16 + quad * 4;
      size_t col = tc0 + wc + j * 16 + l16;
#pragma unroll
      for (int r = 0; r < 4; r++)
        Cf[(row + r) * N + col] = acc[i][j][r] + bias[col];
    }
  }
}

// ---------------- flash attention, key-split x8, 40 KB LDS, 4 blocks/CU ----------------
// (R7 structure; kb now head-major [b][h][l][128] -> contiguous 16 KB K chunks)
__global__ __launch_bounds__(256) void k_attn(const uint16_t* __restrict__ q,
                                              const uint16_t* __restrict__ kb,
                                              const uint16_t* __restrict__ vt,
                                              const float* __restrict__ sims,
                                              const float* __restrict__ beta,
                                              uint16_t* __restrict__ po,
                                              float* __restrict__ pl) {
  __shared__ uint16_t Kl[8192];   // 64 keys x 128 hd, seg-swizzled (16 KB)
  __shared__ uint16_t Vl[8192];   // 128 d x 64 keys, seg-swizzled (16 KB)
  __shared__ uint16_t Pl[4096];   // 4 waves x 32 rows x 32 keys (8 KB)
  const int idx = blockIdx.x;
  const int qbx = idx >> 7, g = idx & 127;
  const int h = g >> 4, b = (g >> 3) & 1, sp = g & 7;
  const int q0 = qbx * 128;
  const int tid = threadIdx.x, lane = tid & 63, w = tid >> 6;
  const int quad = lane >> 4, l16 = lane & 15;
  const float wsplit =
      __builtin_amdgcn_exp2f(sims[b * 4 + (sp >> 1)] * beta[0] * 1.44269504f);
  uint16_t* Pw = Pl + w * 1024;

  union { uint32_t u[4]; bf16x8 v; } Oc;
#pragma unroll
  for (int j = 0; j < 4; j++) Oc.u[j] = 0x3F803F80u;
  const bf16x8 onesf = Oc.v;

  bf16x8 qf[2][4];
#pragma unroll
  for (int rb = 0; rb < 2; rb++) {
    const uint16_t* qrow =
        q + ((size_t)(b * 1024 + q0 + w * 32 + rb * 16 + l16)) * 1024 + h * 128 + quad * 8;
#pragma unroll
    for (int ks = 0; ks < 4; ks++) qf[rb][ks] = *(const bf16x8*)(qrow + ks * 32);
  }
  f32x4 o[2][8] = {};
  f32x4 o9[2] = {};

  const uint16_t* kptr = kb + ((size_t)(b * 8 + h) * 4096 + sp * 512) * 128;
  const uint16_t* vptr = vt + ((size_t)(b * 8 + h) * 128) * 4096 + sp * 512;

  for (int c = 0; c < 8; c++) {
    __syncthreads(); // prev chunk's frag reads done before restage
#pragma unroll
    for (int ii = 0; ii < 4; ii++) {
      int g2 = tid + ii * 256;
      int row = g2 >> 4, seg = (g2 & 15) ^ (row & 15);
      load_lds16(kptr + row * 128 + seg * 8, Kl + g2 * 8);
    }
#pragma unroll
    for (int ii = 0; ii < 4; ii++) {
      int g2 = tid + ii * 256;
      int row = g2 >> 3, seg = (g2 & 7) ^ (row & 7);
      load_lds16(vptr + (size_t)row * 4096 + seg * 8, Vl + g2 * 8);
    }
    __syncthreads(); // DMA complete
#pragma unroll
    for (int kh = 0; kh < 2; kh++) {
      // QK for this 32-key half; exp2 + P-half spill fused
#pragma unroll
      for (int nb2 = 0; nb2 < 2; nb2++) {
        const int nb = kh * 2 + nb2;
        f32x4 s0 = {}, s1 = {};
#pragma unroll
        for (int ks = 0; ks < 4; ks++) {
          bf16x8 kf = *(const bf16x8*)&Kl[(nb * 16 + l16) * 128 + (((ks * 4 + quad) ^ l16) * 8)];
          s0 = __builtin_amdgcn_mfma_f32_16x16x32_bf16(qf[0][ks], kf, s0, 0, 0, 0);
          s1 = __builtin_amdgcn_mfma_f32_16x16x32_bf16(qf[1][ks], kf, s1, 0, 0, 0);
        }
        const int sl = nb2 * 2 + (l16 >> 3); // key seg within the half (0..3)
#pragma unroll
        for (int r = 0; r < 4; r++) {
          int rp0 = quad * 4 + r;
          Pw[rp0 * 32 + ((sl ^ ((rp0 >> 1) & 3)) * 8) + (l16 & 7)] =
              f2bf(__builtin_amdgcn_exp2f(s0[r]));
          int rp1 = 16 + rp0;
          Pw[rp1 * 32 + ((sl ^ ((rp1 >> 1) & 3)) * 8) + (l16 & 7)] =
              f2bf(__builtin_amdgcn_exp2f(s1[r]));
        }
      }
      __asm__ volatile("s_waitcnt lgkmcnt(0)" ::: "memory"); // wave-local P visibility
      // PV for this half
      const int segp = (quad ^ ((l16 >> 1) & 3)) * 8;
      bf16x8 pf0 = *(const bf16x8*)&Pw[l16 * 32 + segp];
      bf16x8 pf1 = *(const bf16x8*)&Pw[(16 + l16) * 32 + segp];
      const int sq = ((kh * 4 + quad) ^ (l16 & 7)) * 8;
#pragma unroll
      for (int nb = 0; nb < 8; nb++) {
        bf16x8 vf = *(const bf16x8*)&Vl[(nb * 16 + l16) * 64 + sq];
        o[0][nb] = __builtin_amdgcn_mfma_f32_16x16x32_bf16(pf0, vf, o[0][nb], 0, 0, 0);
        o[1][nb] = __builtin_amdgcn_mfma_f32_16x16x32_bf16(pf1, vf, o[1][nb], 0, 0, 0);
      }
      o9[0] = __builtin_amdgcn_mfma_f32_16x16x32_bf16(pf0, onesf, o9[0], 0, 0, 0);
      o9[1] = __builtin_amdgcn_mfma_f32_16x16x32_bf16(pf1, onesf, o9[1], 0, 0, 0);
    }
    kptr += 64 * 128;
    vptr += 64;
  }
  // epilogue: sim-weighted partial O (bf16) + weighted row sums
  const int rowbase = (sp * 16 + b * 8 + h) * 1024 + q0 + w * 32;
#pragma unroll
  for (int rb = 0; rb < 2; rb++)
#pragma unroll
    for (int r = 0; r < 4; r++) {
      int row = rowbase + rb * 16 + quad * 4 + r;
#pragma unroll
      for (int nb = 0; nb < 8; nb++)
        po[(size_t)row * 128 + nb * 16 + l16] = f2bf(o[rb][nb][r] * wsplit);
      if (l16 == 0)
        pl[row] = o9[rb][r] * wsplit;
    }
}

// ---------------- merge 8 key-split partials (plain weighted sum) -> attb ----------------
__global__ __launch_bounds__(256) void k_merge(const uint16_t* __restrict__ po,
                                               const float* __restrict__ pl,
                                               uint16_t* __restrict__ attb) {
  const int bq = blockIdx.x;
  const int b = bq >> 10, qi = bq & 1023;
  const int t = threadIdx.x;
  const int h = t >> 5, d0 = (t & 31) * 4;
  const int bh = b * 8 + h;
  float den = 0.f;
  float acc[4] = {0.f, 0.f, 0.f, 0.f};
#pragma unroll
  for (int s = 0; s < 8; s++) {
    den += pl[(s * 16 + bh) * 1024 + qi];
    union { uint64_t q; uint16_t u[4]; } v;
    v.q = *(const uint64_t*)&po[(((size_t)(s * 16 + bh)) * 1024 + qi) * 128 + d0];
#pragma unroll
    for (int j = 0; j < 4; j++) acc[j] += bf2f(v.u[j]);
  }
  const float inv = 1.0f / den;
  union { uint64_t q; uint16_t u[4]; } o;
#pragma unroll
  for (int j = 0; j < 4; j++) o.u[j] = f2bf(acc[j] * inv);
  *(uint64_t*)&attb[((size_t)(b * 1024 + qi)) * 1024 + h * 128 + d0] = o.q;
}

// ---------------- launch ----------------
extern "C" void kernel_launch(void* const* d_in, const int* in_sizes, int n_in,
                              void* d_out, int out_size, void* d_ws, size_t ws_size,
                              hipStream_t stream) {
  (void)in_sizes; (void)n_in; (void)out_size; (void)ws_size;
  const float* x    = (const float*)d_in[0];
  const float* ctx  = (const float*)d_in[1];
  const float* sims = (const float*)d_in[2];
  const float* Wq   = (const float*)d_in[3];
  const float* Wkv  = (const float*)d_in[4];
  const float* beta = (const float*)d_in[5];
  const float* Wout = (const float*)d_in[6];
  const float* bout = (const float*)d_in[7];
  float* out = (float*)d_out;

  char* ws = (char*)d_ws;
  uint16_t* xb    = (uint16_t*)(ws + 0);           // 4 MB  (dead after fused GEMM)
  uint16_t* ctxb  = (uint16_t*)(ws + (4u << 20));  // 16 MB (dead after fused GEMM)
  uint16_t* wqt   = (uint16_t*)(ws + (20u << 20)); // 2 MB  (dead after fused GEMM)
  uint16_t* wkvt  = (uint16_t*)(ws + (22u << 20)); // 4 MB  (dead after fused GEMM)
  uint16_t* kb    = (uint16_t*)(ws + (32u << 20)); // 16 MB [2][8][4096][128]
  uint16_t* vtb   = (uint16_t*)(ws + (48u << 20)); // 16 MB [16][128][4096]
  float*    pl    = (float*)   (ws + (64u << 20)); // 512 KB [128][1024]
  uint16_t* woutt = (uint16_t*)(ws + (68u << 20)); // 2 MB (live till end)
  uint16_t* qb    = (uint16_t*)(ws + (70u << 20)); // 4 MB (live till attn)
  uint16_t* attb  = (uint16_t*)(ws + (74u << 20)); // 4 MB
  // po (32 MB) reuses 0..32 MB: xb/ctxb/wqt/wkvt all dead by attention time
  uint16_t* po = (uint16_t*)(ws + 0);              // 32 MB [128][1024][128]

  const float LOG2E = 1.44269504f;
  const float qscale = 0.03125f * LOG2E;

  k_prep<<<14336, 256, 0, stream>>>(x, ctx, Wq, Wkv, Wout, xb, ctxb, wqt, wkvt, woutt, qscale);
  k_gemm_fused<<<1152, 256, 0, stream>>>(ctxb, wkvt, xb, wqt, kb, vtb, qb);
  k_attn<<<1024, 256, 0, stream>>>(qb, kb, vtb, sims, beta, po, pl);
  k_merge<<<2048, 256, 0, stream>>>(po, pl, attb);
  k_gemm64<<<dim3(16, 32), 256, 0, stream>>>(attb, woutt, out, bout, 2048, 1024, 1024);
}